// Round 2
// 1889.399 us; speedup vs baseline: 1.1014x; 1.1014x over previous
//
#include <hip/hip_runtime.h>
#include <hip/hip_bf16.h>
#include <cstdint>
#include <cstddef>

// Problem dims (from setup_inputs)
#define BT 2048
#define V  32000
#define HS 2048
#define HT 4096

typedef float f32x4 __attribute__((ext_vector_type(4)));
typedef __bf16 bf16x8 __attribute__((ext_vector_type(8)));
typedef unsigned short u16x8 __attribute__((ext_vector_type(8)));

__device__ __forceinline__ unsigned short f2bf(float f) {
    union { float f; unsigned u; } x; x.f = f;
    unsigned u = x.u;
    unsigned r = (u + 0x7FFFu + ((u >> 16) & 1u)) >> 16;  // RNE fp32->bf16
    return (unsigned short)r;
}

// Async global->LDS, 16 B per lane. LDS dst is wave-uniform base + lane*16.
__device__ __forceinline__ void gload_lds16(const void* g, void* l) {
    __builtin_amdgcn_global_load_lds(
        (__attribute__((address_space(1))) void*)(void*)g,
        (__attribute__((address_space(3))) void*)l, 16, 0, 0);
}

// ---------------------------------------------------------------------------
// fp32 -> bf16 elementwise (8 elems / thread). Memory-bound.
__global__ __launch_bounds__(256)
void convert_bf16(const float* __restrict__ in, unsigned short* __restrict__ out,
                  int n8) {
    int i = blockIdx.x * 256 + threadIdx.x;
    if (i >= n8) return;
    const float4* p = (const float4*)in + (size_t)i * 2;
    float4 a = p[0], b = p[1];
    u16x8 r;
    r[0] = f2bf(a.x); r[1] = f2bf(a.y); r[2] = f2bf(a.z); r[3] = f2bf(a.w);
    r[4] = f2bf(b.x); r[5] = f2bf(b.y); r[6] = f2bf(b.z); r[7] = f2bf(b.w);
    ((u16x8*)out)[i] = r;
}

// ---------------------------------------------------------------------------
// 256x256-tile, BK=64, 8-wave, 8-phase GEMM with counted vmcnt (m201 template).
// C[M][N] = A[M][K] @ W[N][K]^T, bf16 in, fp32 out.
//
// Per iteration = 2 K-tiles (2i->buf0, 2i+1->buf1), 8 phases. Each phase:
//   { ds_read frags | issue 2 stage loads | bar | lgkmcnt(0) | MFMA*16 | bar }
// vmcnt(6) only at P3/P7 (retires exactly the 8 loads of the buffer read next).
// Stage units are quad-aligned so a region staged at phase p was last read at
// phase <= p-1 (all waves past barrier_B(p-1) => their reads consumed).
// LDS 128 KiB = 2 buf x (A 256x64 + B 256x64) bf16. Rows are 128 B; chunk slot
// XOR swizzle slot = chunk ^ (row&7) (2-way = free); global source pre-swizzled
// so global_load_lds dest stays linear (both-sides-or-neither rule).
template <int K>
__global__ __launch_bounds__(512, 2)
void gemm_bf16_256(const unsigned short* __restrict__ A,
                   const unsigned short* __restrict__ W,
                   float* __restrict__ C) {
    __shared__ __align__(16) unsigned short As[2][256 * 64];
    __shared__ __align__(16) unsigned short Bs[2][256 * 64];

    const int tid = threadIdx.x;

    // XCD-aware chunked swizzle: 1000 wgs = 8 XCDs x 125; within an XCD chunk
    // m varies fastest -> W-strip stays in that XCD's L2. 1000 % 8 == 0 -> bijective.
    constexpr int GX = BT / 256;                     // 8
    constexpr int PERX = (BT / 256) * (V / 256) / 8; // 125
    const int wg  = blockIdx.y * GX + blockIdx.x;
    const int swz = (wg & 7) * PERX + (wg >> 3);
    const int m0 = (swz & 7) * 256;
    const int n0 = (swz >> 3) * 256;

    const int wave = tid >> 6, lane = tid & 63;
    const int ln15 = lane & 15, qlane = lane >> 4;
    const int wr = wave >> 2;   // 0..1 -> 128 output rows each
    const int wc = wave & 3;    // 0..3 -> 64 output cols each

    // ---- staging constants (per-thread) ----
    const int trow = tid >> 3;                      // 0..63
    const int cs8  = tid & 7;                       // LDS 16B-chunk slot
    const int gch  = cs8 ^ (trow & 7);              // pre-swizzled global chunk
    const int arow = trow + (tid >= 256 ? 96 : 0);  // A rows: quad-paired halves

    const unsigned short* pA = A + (size_t)(m0 + arow) * K + gch * 8;
    const unsigned short* pB = W + (size_t)(n0 + trow) * K + gch * 8;
    const int aoff = arow * 64 + cs8 * 8;
    const int boff = trow * 64 + cs8 * 8;

#define SA(kt, b, j) gload_lds16(pA + (size_t)(j) * 32 * K + (size_t)(kt) * 64, \
                                 &As[b][(j) * 2048 + aoff])
#define SB(kt, b, j) gload_lds16(pB + (size_t)(j) * 64 * K + (size_t)(kt) * 64, \
                                 &Bs[b][(j) * 4096 + boff])
#define BAR() __builtin_amdgcn_s_barrier()
#define VM6() asm volatile("s_waitcnt vmcnt(6)" ::: "memory")
#define VM0() asm volatile("s_waitcnt vmcnt(0)" ::: "memory")
#define LGKM0() do { asm volatile("s_waitcnt lgkmcnt(0)" ::: "memory"); \
                     __builtin_amdgcn_sched_barrier(0); } while (0)

    // ---- compute-side constants ----
    // data chunk ks*4+qlane lives at slot (chunk ^ (row&7)); row&7 == ln15&7.
    const int sl0 = ((qlane)     ^ (ln15 & 7)) * 8;
    const int sl1 = ((qlane ^ 4) ^ (ln15 & 7)) * 8;
    const int abase = (wr * 128 + ln15) * 64;
    const int bbase = (wc * 64  + ln15) * 64;

    f32x4 acc[8][4];
#pragma unroll
    for (int i = 0; i < 8; ++i)
#pragma unroll
        for (int j = 0; j < 4; ++j)
            acc[i][j] = f32x4{0.f, 0.f, 0.f, 0.f};

    bf16x8 bfv[4][2];   // B frags for whole tile (loaded at P0/P4)
    bf16x8 af[2][2];    // A frags for current quad

#define LOADB(b) do { _Pragma("unroll") for (int cb = 0; cb < 4; ++cb) {      \
        bfv[cb][0] = *(const bf16x8*)&Bs[b][bbase + cb * 1024 + sl0];         \
        bfv[cb][1] = *(const bf16x8*)&Bs[b][bbase + cb * 1024 + sl1]; } } while (0)
#define LOADA(b, q) do { _Pragma("unroll") for (int i = 0; i < 2; ++i) {      \
        af[i][0] = *(const bf16x8*)&As[b][abase + ((q) * 2 + i) * 1024 + sl0];\
        af[i][1] = *(const bf16x8*)&As[b][abase + ((q) * 2 + i) * 1024 + sl1]; } } while (0)
#define MM(q) do { __builtin_amdgcn_s_setprio(1);                             \
        _Pragma("unroll") for (int ks = 0; ks < 2; ++ks)                      \
        _Pragma("unroll") for (int i = 0; i < 2; ++i)                         \
        _Pragma("unroll") for (int cb = 0; cb < 4; ++cb)                      \
            acc[(q) * 2 + i][cb] = __builtin_amdgcn_mfma_f32_16x16x32_bf16(   \
                af[i][ks], bfv[cb][ks], acc[(q) * 2 + i][cb], 0, 0, 0);       \
        __builtin_amdgcn_s_setprio(0); } while (0)

    // ---- prologue: tile0 complete + tile1 B0..B3,Aq0,Aq1 (14 loads) ----
    SB(0, 0, 0); SB(0, 0, 1); SB(0, 0, 2); SB(0, 0, 3);
    SA(0, 0, 0); SA(0, 0, 1); SA(0, 0, 2); SA(0, 0, 3);
    SB(1, 1, 0); SB(1, 1, 1); SB(1, 1, 2); SB(1, 1, 3);
    SA(1, 1, 0); SA(1, 1, 1);
    VM6();      // tile0's 8 loads landed; 6 (tile1 partial) stay in flight
    BAR();

    constexpr int NT = K / 64;
    constexpr int NI = NT / 2;
    for (int i = 0; i < NI - 1; ++i) {
        const int t2 = 2 * i + 2, t3 = 2 * i + 3;
        // P0
        LOADB(0); LOADA(0, 0); SA(2 * i + 1, 1, 2); SA(2 * i + 1, 1, 3);
        BAR(); LGKM0(); MM(0); BAR();
        // P1
        LOADA(0, 1); SB(t2, 0, 0); SB(t2, 0, 1);
        BAR(); LGKM0(); MM(1); BAR();
        // P2
        LOADA(0, 2); SB(t2, 0, 2); SB(t2, 0, 3);
        BAR(); LGKM0(); MM(2); BAR();
        // P3
        LOADA(0, 3); SA(t2, 0, 0); SA(t2, 0, 1);
        BAR(); LGKM0(); MM(3); VM6(); BAR();
        // P4
        LOADB(1); LOADA(1, 0); SA(t2, 0, 2); SA(t2, 0, 3);
        BAR(); LGKM0(); MM(0); BAR();
        // P5
        LOADA(1, 1); SB(t3, 1, 0); SB(t3, 1, 1);
        BAR(); LGKM0(); MM(1); BAR();
        // P6
        LOADA(1, 2); SB(t3, 1, 2); SB(t3, 1, 3);
        BAR(); LGKM0(); MM(2); BAR();
        // P7
        LOADA(1, 3); SA(t3, 1, 0); SA(t3, 1, 1);
        BAR(); LGKM0(); MM(3); VM6(); BAR();
    }
    // ---- final iteration (tiles NT-2, NT-1): no further prefetch ----
    LOADB(0); LOADA(0, 0); SA(NT - 1, 1, 2); SA(NT - 1, 1, 3);
    BAR(); LGKM0(); MM(0); BAR();
    LOADA(0, 1); BAR(); LGKM0(); MM(1); BAR();
    LOADA(0, 2); BAR(); LGKM0(); MM(2); BAR();
    LOADA(0, 3); BAR(); LGKM0(); MM(3); VM0(); BAR();
    LOADB(1); LOADA(1, 0); BAR(); LGKM0(); MM(0); BAR();
    LOADA(1, 1); BAR(); LGKM0(); MM(1); BAR();
    LOADA(1, 2); BAR(); LGKM0(); MM(2); BAR();
    LOADA(1, 3); LGKM0(); MM(3);

    // ---- epilogue: C/D layout col=lane&15, row=qlane*4+reg ----
#pragma unroll
    for (int rb = 0; rb < 8; ++rb) {
        const int row = m0 + wr * 128 + rb * 16 + qlane * 4;
#pragma unroll
        for (int cb = 0; cb < 4; ++cb) {
            const int col = n0 + wc * 64 + cb * 16 + ln15;
#pragma unroll
            for (int r = 0; r < 4; ++r)
                C[(size_t)(row + r) * V + col] = acc[rb][cb][r];
        }
    }
#undef SA
#undef SB
#undef BAR
#undef VM6
#undef VM0
#undef LGKM0
#undef LOADB
#undef LOADA
#undef MM
}

// ---------------------------------------------------------------------------
// FALLBACK GEMM (fp32 inputs, convert-in-kernel) — used only if ws_size can't
// hold the bf16 copies.
template <int K>
__global__ __launch_bounds__(256, 2)
void gemm_f32(const float* __restrict__ A, const float* __restrict__ W,
              float* __restrict__ C) {
    __shared__ __align__(16) unsigned short As[128][40];
    __shared__ __align__(16) unsigned short Bs[128][40];

    const int tid  = threadIdx.x;
    const int m0   = blockIdx.x * 128;
    const int n0   = blockIdx.y * 128;
    const int wave = tid >> 6;
    const int lane = tid & 63;
    const int ln15 = lane & 15;
    const int q    = lane >> 4;
    const int wr   = wave >> 1;
    const int wc   = wave & 1;

    f32x4 acc[4][4];
#pragma unroll
    for (int i = 0; i < 4; ++i)
#pragma unroll
        for (int j = 0; j < 4; ++j)
            acc[i][j] = f32x4{0.f, 0.f, 0.f, 0.f};

    const int lr = tid >> 3;
    const int lc = (tid & 7) * 4;

    for (int k0 = 0; k0 < K; k0 += 32) {
#pragma unroll
        for (int p = 0; p < 4; ++p) {
            const int r = lr + p * 32;
            const float4 av = *(const float4*)&A[(size_t)(m0 + r) * K + k0 + lc];
            const float4 bv = *(const float4*)&W[(size_t)(n0 + r) * K + k0 + lc];
            As[r][lc + 0] = f2bf(av.x); As[r][lc + 1] = f2bf(av.y);
            As[r][lc + 2] = f2bf(av.z); As[r][lc + 3] = f2bf(av.w);
            Bs[r][lc + 0] = f2bf(bv.x); Bs[r][lc + 1] = f2bf(bv.y);
            Bs[r][lc + 2] = f2bf(bv.z); Bs[r][lc + 3] = f2bf(bv.w);
        }
        __syncthreads();

        bf16x8 af[4], bfr[4];
#pragma unroll
        for (int t = 0; t < 4; ++t) {
            af[t]  = *(const bf16x8*)&As[wr * 64 + t * 16 + ln15][q * 8];
            bfr[t] = *(const bf16x8*)&Bs[wc * 64 + t * 16 + ln15][q * 8];
        }
#pragma unroll
        for (int i = 0; i < 4; ++i)
#pragma unroll
            for (int j = 0; j < 4; ++j)
                acc[i][j] = __builtin_amdgcn_mfma_f32_16x16x32_bf16(
                    af[i], bfr[j], acc[i][j], 0, 0, 0);
        __syncthreads();
    }

#pragma unroll
    for (int i = 0; i < 4; ++i) {
        const int row = m0 + wr * 64 + i * 16 + q * 4;
#pragma unroll
        for (int j = 0; j < 4; ++j) {
            const int col = n0 + wc * 64 + j * 16 + ln15;
#pragma unroll
            for (int r = 0; r < 4; ++r)
                C[(size_t)(row + r) * V + col] = acc[i][j][r];
        }
    }
}

// ---------------------------------------------------------------------------
// Fused per-row stats + loss. Phase 1: online logsumexp (branchless, float4).
// Phase 2: JSD accumulation + hard CE. One atomicAdd per row.
__device__ __forceinline__ void ol_update(float& m, float& s, float x) {
    float M = fmaxf(m, x);
    s = s * __expf(m - M) + __expf(x - M);
    m = M;
}

__global__ __launch_bounds__(256)
void stats_loss(const float* __restrict__ S, const float* __restrict__ T,
                const int* __restrict__ labels, float* __restrict__ out) {
    const int row = blockIdx.x;
    const int tid = threadIdx.x;
    const float4* s4 = (const float4*)(S + (size_t)row * V);
    const float4* t4 = (const float4*)(T + (size_t)row * V);
    const int NV4 = V / 4;  // 8000

    float ms = -1e30f, ss = 0.f, mt = -1e30f, st = 0.f;
    for (int i = tid; i < NV4; i += 256) {
        float4 a = s4[i];
        ol_update(ms, ss, a.x); ol_update(ms, ss, a.y);
        ol_update(ms, ss, a.z); ol_update(ms, ss, a.w);
        float4 b = t4[i];
        ol_update(mt, st, b.x); ol_update(mt, st, b.y);
        ol_update(mt, st, b.z); ol_update(mt, st, b.w);
    }

    __shared__ float rm[256], rs[256];
    // student lse
    rm[tid] = ms; rs[tid] = ss; __syncthreads();
    for (int off = 128; off > 0; off >>= 1) {
        if (tid < off) {
            float m1 = rm[tid], s1 = rs[tid];
            float m2 = rm[tid + off], s2 = rs[tid + off];
            float M = fmaxf(m1, m2);
            rm[tid] = M;
            rs[tid] = s1 * __expf(m1 - M) + s2 * __expf(m2 - M);
        }
        __syncthreads();
    }
    const float lseS = rm[0] + __logf(rs[0]);
    __syncthreads();
    // teacher lse
    rm[tid] = mt; rs[tid] = st; __syncthreads();
    for (int off = 128; off > 0; off >>= 1) {
        if (tid < off) {
            float m1 = rm[tid], s1 = rs[tid];
            float m2 = rm[tid + off], s2 = rs[tid + off];
            float M = fmaxf(m1, m2);
            rm[tid] = M;
            rs[tid] = s1 * __expf(m1 - M) + s2 * __expf(m2 - M);
        }
        __syncthreads();
    }
    const float lseT = rm[0] + __logf(rs[0]);
    __syncthreads();

    // Phase 2: JSD terms
    float acc = 0.f;
    for (int i = tid; i < NV4; i += 256) {
        float4 a = s4[i];
        float4 b = t4[i];
#pragma unroll
        for (int c = 0; c < 4; ++c) {
            float ls = ((const float*)&a)[c] - lseS;
            float lt = ((const float*)&b)[c] - lseT;
            float ps = __expf(ls);
            float pt = __expf(lt);
            float lm = __logf(0.5f * (ps + pt));
            acc += ps * (ls - lm) + pt * (lt - lm);
        }
    }
    rm[tid] = acc; __syncthreads();
    for (int off = 128; off > 0; off >>= 1) {
        if (tid < off) rm[tid] += rm[tid + off];
        __syncthreads();
    }
    if (tid == 0) {
        const int lab = labels[row];
        float nll = 0.f;
        if (lab != -100) nll = lseS - S[(size_t)row * V + lab];
        const float contrib = (0.5f * nll + 0.25f * rm[0]) * (1.0f / (float)BT);
        atomicAdd(out, contrib);
    }
}

__global__ void zero_out(float* out) { out[0] = 0.f; }

// ---------------------------------------------------------------------------
extern "C" void kernel_launch(void* const* d_in, const int* in_sizes, int n_in,
                              void* d_out, int out_size, void* d_ws, size_t ws_size,
                              hipStream_t stream) {
    const float* s_in   = (const float*)d_in[0];  // (BT, HS)
    const float* s_w    = (const float*)d_in[1];  // (V, HS)
    const float* t_in   = (const float*)d_in[2];  // (BT, HT)
    const float* t_w    = (const float*)d_in[3];  // (V, HT)
    const int*   labels = (const int*)d_in[4];    // (BT,)
    float* out = (float*)d_out;

    char* ws = (char*)d_ws;
    const size_t logit_bytes = (size_t)BT * V * sizeof(float);      // 262,144,000
    float* s_logits = (float*)ws;
    float* t_logits = (float*)(ws + logit_bytes);
    size_t off = 2 * logit_bytes;

    const size_t as_bytes = (size_t)BT * HS * 2;    //   8,388,608
    const size_t ws_bytes = (size_t)V  * HS * 2;    // 131,072,000
    const size_t at_bytes = (size_t)BT * HT * 2;    //  16,777,216
    const size_t wt_bytes = (size_t)V  * HT * 2;    // 262,144,000
    const size_t fast_total = off + as_bytes + ws_bytes + at_bytes + wt_bytes + 4096;

    zero_out<<<1, 1, 0, stream>>>(out);

    if (ws_size >= fast_total) {
        unsigned short* abf_s = (unsigned short*)(ws + off);  off += as_bytes;
        unsigned short* wbf_s = (unsigned short*)(ws + off);  off += ws_bytes;
        unsigned short* abf_t = (unsigned short*)(ws + off);  off += at_bytes;
        unsigned short* wbf_t = (unsigned short*)(ws + off);  off += wt_bytes;

        const int n8_as = BT * HS / 8, n8_ws = V * HS / 8;
        const int n8_at = BT * HT / 8, n8_wt = V * HT / 8;
        convert_bf16<<<(n8_as + 255) / 256, 256, 0, stream>>>(s_in, abf_s, n8_as);
        convert_bf16<<<(n8_ws + 255) / 256, 256, 0, stream>>>(s_w,  wbf_s, n8_ws);
        convert_bf16<<<(n8_at + 255) / 256, 256, 0, stream>>>(t_in, abf_t, n8_at);
        convert_bf16<<<(n8_wt + 255) / 256, 256, 0, stream>>>(t_w,  wbf_t, n8_wt);

        gemm_bf16_256<HS><<<dim3(BT / 256, V / 256), 512, 0, stream>>>(abf_s, wbf_s, s_logits);
        gemm_bf16_256<HT><<<dim3(BT / 256, V / 256), 512, 0, stream>>>(abf_t, wbf_t, t_logits);
    } else {
        gemm_f32<HS><<<dim3(BT / 128, V / 128), 256, 0, stream>>>(s_in, s_w, s_logits);
        gemm_f32<HT><<<dim3(BT / 128, V / 128), 256, 0, stream>>>(t_in, t_w, t_logits);
    }

    stats_loss<<<BT, 256, 0, stream>>>(s_logits, t_logits, labels, out);
}